// Round 16
// baseline (1701.747 us; speedup 1.0000x reference)
//
#include <hip/hip_runtime.h>
#include <math.h>

#define D_MODEL 256
#define NHEAD   8
#define D_K     32
#define LSEQ    2048
#define BATCH   2
#define ROWS    (BATCH * LSEQ)   // 4096
#define D_FF    1024
#define UTOP    38
#define CAP     128

// ---------------------------------------------------------------------------
// Embedding + positional encoding
// ---------------------------------------------------------------------------
__global__ __launch_bounds__(256) void k_embed(const float* __restrict__ x,
                                               const float* __restrict__ w,
                                               const float* __restrict__ b,
                                               float* __restrict__ h) {
    int row = blockIdx.x;           // b*L + l
    int l   = row & (LSEQ - 1);
    int d   = threadIdx.x;
    __shared__ float xs[32];
    if (d < 32) xs[d] = x[row * 32 + d];
    __syncthreads();
    float acc = 0.f;
#pragma unroll
    for (int i = 0; i < 32; ++i) acc += xs[i] * w[i * D_MODEL + d];
    acc = (acc + b[d]) * 16.0f;     // sqrt(256)
    int m = d >> 1;
    float div = expf(-(float)(2 * m) * (9.210340371976184f / 256.0f)); // ln(1e4)/256
    float ang = (float)l * div;
    float pe = (d & 1) ? cosf(ang) : sinf(ang);
    h[row * D_MODEL + d] = acc + pe;
}

// ---------------------------------------------------------------------------
// Shared fp32 tiled GEMM body: C[64x64 tile] = A[M,K(lda)] @ W[K,N] (+ bias)
// MODE 0: plain   MODE 1: relu   MODE 2: scatter to q/k/v layout [B,H,L,32]
// ---------------------------------------------------------------------------
template <int MODE>
__device__ __forceinline__ void gemm_body(const float* __restrict__ A, int lda,
                                          const float* __restrict__ W, int N,
                                          const float* __restrict__ bias, bool doBias,
                                          float* __restrict__ C, int K,
                                          int m0, int n0) {
    __shared__ float As[16][68];
    __shared__ float Ws[16][68];
    const int t  = threadIdx.x;
    const int tx = t & 15, ty = t >> 4;
    float acc[4][4] = {};
    for (int k0 = 0; k0 < K; k0 += 16) {
        {
            int mr = t >> 2, kc = (t & 3) * 4;
            float4 av = *(const float4*)&A[(size_t)(m0 + mr) * lda + k0 + kc];
            As[kc + 0][mr] = av.x; As[kc + 1][mr] = av.y;
            As[kc + 2][mr] = av.z; As[kc + 3][mr] = av.w;
            int kr = t >> 4, nc = (t & 15) * 4;
            *(float4*)&Ws[kr][nc] = *(const float4*)&W[(size_t)(k0 + kr) * N + n0 + nc];
        }
        __syncthreads();
#pragma unroll
        for (int k = 0; k < 16; ++k) {
            float4 a4 = *(const float4*)&As[k][ty * 4];
            float4 w4 = *(const float4*)&Ws[k][tx * 4];
            float av[4] = {a4.x, a4.y, a4.z, a4.w};
            float wv[4] = {w4.x, w4.y, w4.z, w4.w};
#pragma unroll
            for (int i = 0; i < 4; ++i)
#pragma unroll
                for (int j = 0; j < 4; ++j) acc[i][j] += av[i] * wv[j];
        }
        __syncthreads();
    }
#pragma unroll
    for (int i = 0; i < 4; ++i) {
        int row = m0 + ty * 4 + i;
#pragma unroll
        for (int j = 0; j < 4; ++j) {
            int col = n0 + tx * 4 + j;
            float v = acc[i][j];
            if (doBias) v += bias[col];
            if (MODE == 1) v = fmaxf(v, 0.f);
            if (MODE == 2) {
                int bb = row >> 11, ll = row & (LSEQ - 1);
                int hh = col >> 5, dd = col & 31;
                C[(((size_t)(bb * NHEAD + hh) * LSEQ) + ll) * D_K + dd] = v;
            } else {
                C[(size_t)row * N + col] = v;
            }
        }
    }
}

// QKV fused: blockIdx.z selects {wq,wk,wv}; scatters to [B,H,L,32] at out+z*1M.
__global__ __launch_bounds__(256) void k_qkv(const float* __restrict__ A,
                                             const float* __restrict__ wq,
                                             const float* __restrict__ wk,
                                             const float* __restrict__ wv,
                                             const float* __restrict__ bq,
                                             const float* __restrict__ bk,
                                             const float* __restrict__ bv,
                                             float* __restrict__ out) {
    int z = blockIdx.z;
    const float* W = z == 0 ? wq : (z == 1 ? wk : wv);
    const float* B = z == 0 ? bq : (z == 1 ? bk : bv);
    gemm_body<2>(A, 256, W, 256, B, true, out + (size_t)z * (1 << 20), 256,
                 blockIdx.x * 64, blockIdx.y * 64);
}

// split-K GEMM: blockIdx.z = K-half; partial z to Cbase + z*1M; bias on z=0 only.
__global__ __launch_bounds__(256) void k_gemm_sk(const float* __restrict__ A, int lda,
                                                 const float* __restrict__ W,
                                                 const float* __restrict__ bias,
                                                 float* __restrict__ Cbase,
                                                 int N, int Ksub) {
    int z = blockIdx.z;
    gemm_body<0>(A + (size_t)z * Ksub, lda, W + (size_t)z * Ksub * N, N, bias, z == 0,
                 Cbase + (size_t)z * (1 << 20), Ksub, blockIdx.x * 64, blockIdx.y * 64);
}

// ff1: relu GEMM, N=1024
__global__ __launch_bounds__(256) void k_ff1(const float* __restrict__ A,
                                             const float* __restrict__ W,
                                             const float* __restrict__ bias,
                                             float* __restrict__ C) {
    gemm_body<1>(A, 256, W, 1024, bias, true, C, 256, blockIdx.x * 64, blockIdx.y * 64);
}

// ---------------------------------------------------------------------------
// Fused ProbSparse attention v13 — 1 ROW PER WAVE for occupancy.
// R14 analysis: wave-work ~23K cyc (QK + serial epilogue chains) vs issue
// slots at 10 waves/CU = measured VALUBusy 50% -> issue-slot-starved.
// Fix: q 32 + keys 32 regs (~85 live) -> __launch_bounds__(256,5) -> 5
// blocks/CU = 20 waves: double the slot supply over the latency chains.
// Full-dim dots (no d-split / combine shuffles). Chunk-major LDS layout +
// shared staging (R13-verified), triple-buffer vmcnt(2) + s_barrier pacing
// (R14-verified), pivot bitonic + 128-bitonic threshold + PV (verified).
// ---------------------------------------------------------------------------
__device__ __forceinline__ unsigned int sortkey(float f) {
    unsigned int u = __float_as_uint(f);
    return (u & 0x80000000u) ? ~u : (u | 0x80000000u);
}
__device__ __forceinline__ float key2f(unsigned int u) {
    unsigned int b = (u & 0x80000000u) ? (u ^ 0x80000000u) : ~u;
    return __uint_as_float(b);
}
__device__ __forceinline__ void gload_lds16(const float* src, float* ldsDst) {
    __builtin_amdgcn_global_load_lds(
        (const __attribute__((address_space(1))) unsigned int*)src,
        (__attribute__((address_space(3))) unsigned int*)ldsDst,
        16, 0, 0);
}

__global__ __launch_bounds__(256, 5) void k_attn(const float* __restrict__ Q,
                                                 const float* __restrict__ Kt,
                                                 const float* __restrict__ Vt,
                                                 float* __restrict__ ctxb) {
    __shared__ float          Kl[3][2048];      // 24 KB  K tile triple-buffer
    __shared__ unsigned int   lvk[4][CAP];      // 2 KB   candidate keys (1 row/wave)
    __shared__ unsigned short lix[4][CAP];      // 1 KB   candidate indices
    __shared__ int            lcnt[4];

    const int tid   = threadIdx.x;
    const int lane  = tid & 63;
    const int wid   = tid >> 6;
    // XCD swizzle: grid 8192 = 8 XCDs x 1024 (bijective).
    const int lbid  = (blockIdx.x & 7) * 1024 + (blockIdx.x >> 3);
    const int bh    = lbid >> 9;                // 16 bh x 512 chunks
    const int chunk = lbid & 511;
    const int row   = chunk * 4 + wid;          // 1 row per wave
    const int b     = bh >> 3, hh = bh & 7;

    const float* Kb = Kt + (size_t)bh * LSEQ * D_K;
    const float* Vb = Vt + (size_t)bh * LSEQ * D_K;
    const float* qp = Q + ((size_t)bh * LSEQ + row) * D_K;

    const float scale = 0.17677669529663687f;   // 1/sqrt(32)
    float q[32];
#pragma unroll
    for (int i = 0; i < 32; ++i) q[i] = qp[i] * scale;

    // Stage tile T (shared): wave wid stages granules g = wid*2+{0,1}.
    // Granule g = dim-chunk g of all 64 keys (lane supplies key `lane`):
    //   src = Kb + T*2048 + lane*32 + g*4, dst = Kl[SLOT] + g*1KB (+lane*16B HW)
#define STAGE(T, SLOT)                                                          \
    {                                                                           \
        const int g0_ = wid * 2, g1_ = wid * 2 + 1;                             \
        gload_lds16(Kb + (size_t)(T) * 2048 + lane * 32 + g0_ * 4,              \
                    &Kl[SLOT][g0_ * 256]);                                      \
        gload_lds16(Kb + (size_t)(T) * 2048 + lane * 32 + g1_ * 4,              \
                    &Kl[SLOT][g1_ * 256]);                                      \
    }

    // ---- single pass: full dots -> registers, lane-max -----------------
    unsigned int kk[32];
    unsigned int lm = 0u;

    STAGE(0, 0)
    STAGE(1, 1)
    asm volatile("s_waitcnt vmcnt(2)" ::: "memory");
    __builtin_amdgcn_s_barrier();

#pragma unroll
    for (int t = 0; t < 32; ++t) {
        const int slot = t % 3;               // literal under full unroll
        if (t < 30) STAGE(t + 2, (t + 2) % 3)
        float a = 0.f;
#pragma unroll
        for (int u = 0; u < 8; ++u) {
            float4 kv = *(const float4*)&Kl[slot][u * 256 + lane * 4];
            a += q[u*4+0]*kv.x + q[u*4+1]*kv.y + q[u*4+2]*kv.z + q[u*4+3]*kv.w;
        }
        kk[t] = sortkey(a);
        if (kk[t] > lm) lm = kk[t];
        if (t < 31) {
            if (t < 30) asm volatile("s_waitcnt vmcnt(2)" ::: "memory");
            else        asm volatile("s_waitcnt vmcnt(0)" ::: "memory");
            __builtin_amdgcn_s_barrier();
        }
    }

    // ---- pivot: bitonic-sort 64 lane-maxes, broadcast via shfl ---------
    unsigned int Tpiv;
    float        rmaxf;
    {
        unsigned int v = lm;
#pragma unroll
        for (int k = 2; k <= 64; k <<= 1) {
#pragma unroll
            for (int j = k >> 1; j >= 1; j >>= 1) {
                unsigned int pv = (unsigned int)__shfl_xor((int)v, j);
                bool lower = ((lane & j) == 0);
                bool up    = ((lane & k) == 0);
                unsigned int mn = v < pv ? v : pv;
                unsigned int mx = v < pv ? pv : v;
                v = (lower == up) ? mn : mx;
            }
        }
        Tpiv  = (unsigned int)__shfl((int)v, 26);  // 38th-largest lane-max
        rmaxf = key2f((unsigned int)__shfl((int)v, 63));
    }
    if (lane == 0) lcnt[wid] = 0;

    // ---- push candidates >= pivot from registers (per-wave list) -------
#pragma unroll
    for (int j = 0; j < 32; ++j) {
        if (kk[j] >= Tpiv) {
            int s = atomicAdd(&lcnt[wid], 1);
            if (s < CAP) {
                lvk[wid][s] = kk[j];
                lix[wid][s] = (unsigned short)(j * 64 + lane);
            }
        }
    }

    // ---- exact threshold via 128-wide bitonic, softmax, PV -------------
    int cnt = lcnt[wid]; if (cnt > CAP) cnt = CAP;

    unsigned int v0 = (lane < cnt)      ? lvk[wid][lane]      : 0u;
    unsigned int v1 = (64 + lane < cnt) ? lvk[wid][64 + lane] : 0u;
#pragma unroll
    for (int k = 2; k <= 128; k <<= 1) {
#pragma unroll
        for (int j = k >> 1; j >= 1; j >>= 1) {
            if (j >= 64) {
                bool up0 = ((lane & k) == 0);
                unsigned int mn = v0 < v1 ? v0 : v1;
                unsigned int mx = v0 < v1 ? v1 : v0;
                v0 = up0 ? mn : mx;
                v1 = up0 ? mx : mn;
            } else {
                unsigned int p0 = (unsigned int)__shfl_xor((int)v0, j);
                unsigned int p1 = (unsigned int)__shfl_xor((int)v1, j);
                bool lower = ((lane & j) == 0);
                bool up0 = (((lane) & k) == 0);
                bool up1 = (((64 + lane) & k) == 0);
                v0 = (lower == up0) ? (v0 < p0 ? v0 : p0) : (v0 < p0 ? p0 : v0);
                v1 = (lower == up1) ? (v1 < p1 ? v1 : p1) : (v1 < p1 ? p1 : v1);
            }
        }
    }
    const unsigned int thrkey = (unsigned int)__shfl((int)v1, 26); // idx 90

    float psum = 0.f;
    for (int i = lane; i < cnt; i += 64) {
        unsigned int key = lvk[wid][i];
        if (key >= thrkey) psum += expf(key2f(key) - rmaxf);
    }
#pragma unroll
    for (int off = 32; off >= 1; off >>= 1) psum += __shfl_xor(psum, off);
    float inv = 1.0f / psum;

    const int h = lane >> 5;
    const int p = lane & 31;
    float acc = 0.f;
    for (int i = h; i < cnt; i += 2) {
        unsigned int key = lvk[wid][i];
        float w = (key >= thrkey) ? expf(key2f(key) - rmaxf) : 0.f;
        acc += w * Vb[(size_t)lix[wid][i] * D_K + p];
    }
    acc += __shfl_xor(acc, 32);
    if (lane < 32)
        ctxb[((size_t)(b * LSEQ) + row) * D_MODEL + hh * D_K + p] = acc * inv;
}

// ---------------------------------------------------------------------------
// Residual add (two partials) + LayerNorm over 256, in place into h.
// ---------------------------------------------------------------------------
__global__ __launch_bounds__(64) void k_addln2(float* __restrict__ h,
                                               const float* __restrict__ a1,
                                               const float* __restrict__ a2,
                                               const float* __restrict__ g,
                                               const float* __restrict__ bb) {
    int row = blockIdx.x, lane = threadIdx.x;
    float4 hv = *(const float4*)&h[(size_t)row * D_MODEL + lane * 4];
    float4 v1 = *(const float4*)&a1[(size_t)row * D_MODEL + lane * 4];
    float4 v2 = *(const float4*)&a2[(size_t)row * D_MODEL + lane * 4];
    float x0 = hv.x + v1.x + v2.x, x1 = hv.y + v1.y + v2.y;
    float x2 = hv.z + v1.z + v2.z, x3 = hv.w + v1.w + v2.w;
    float s = x0 + x1 + x2 + x3;
#pragma unroll
    for (int off = 32; off >= 1; off >>= 1) s += __shfl_xor(s, off);
    float mean = s * (1.0f / 256.0f);
    float d0 = x0 - mean, d1 = x1 - mean, d2 = x2 - mean, d3 = x3 - mean;
    float vs = d0 * d0 + d1 * d1 + d2 * d2 + d3 * d3;
#pragma unroll
    for (int off = 32; off >= 1; off >>= 1) vs += __shfl_xor(vs, off);
    float inv = rsqrtf(vs * (1.0f / 256.0f) + 1e-5f);
    float4 gv = *(const float4*)&g[lane * 4];
    float4 bv = *(const float4*)&bb[lane * 4];
    float4 o;
    o.x = d0 * inv * gv.x + bv.x;
    o.y = d1 * inv * gv.y + bv.y;
    o.z = d2 * inv * gv.z + bv.z;
    o.w = d3 * inv * gv.w + bv.w;
    *(float4*)&h[(size_t)row * D_MODEL + lane * 4] = o;
}

// ---------------------------------------------------------------------------
// Decoder head
// ---------------------------------------------------------------------------
__global__ __launch_bounds__(64) void k_dec(const float* __restrict__ h,
                                            const float* __restrict__ w,
                                            const float* __restrict__ b,
                                            float* __restrict__ out) {
    int row = blockIdx.x, lane = threadIdx.x;
    int c = lane & 7, part = lane >> 3;   // 8 parts x 32 dims
    float acc = 0.f;
    int d0 = part * 32;
#pragma unroll
    for (int dd = 0; dd < 32; ++dd) acc += h[(size_t)row * D_MODEL + d0 + dd] * w[(d0 + dd) * 8 + c];
    acc += __shfl_xor(acc, 8);
    acc += __shfl_xor(acc, 16);
    acc += __shfl_xor(acc, 32);
    if (lane < 8) out[(size_t)row * 8 + c] = acc + b[c];
}

// ---------------------------------------------------------------------------
extern "C" void kernel_launch(void* const* d_in, const int* in_sizes, int n_in,
                              void* d_out, int out_size, void* d_ws, size_t ws_size,
                              hipStream_t stream) {
    const float* x     = (const float*)d_in[0];
    const float* emb_w = (const float*)d_in[1];
    const float* emb_b = (const float*)d_in[2];
    const float* wq    = (const float*)d_in[3];
    const float* bq    = (const float*)d_in[4];
    const float* wk    = (const float*)d_in[5];
    const float* bk    = (const float*)d_in[6];
    const float* wv    = (const float*)d_in[7];
    const float* bv    = (const float*)d_in[8];
    const float* wo    = (const float*)d_in[9];
    const float* bo    = (const float*)d_in[10];
    const float* ln1_g = (const float*)d_in[11];
    const float* ln1_b = (const float*)d_in[12];
    const float* ln2_g = (const float*)d_in[13];
    const float* ln2_b = (const float*)d_in[14];
    const float* ff1_w = (const float*)d_in[15];
    const float* ff1_b = (const float*)d_in[16];
    const float* ff2_w = (const float*)d_in[17];
    const float* ff2_b = (const float*)d_in[18];
    const float* dec_w = (const float*)d_in[19];
    const float* dec_b = (const float*)d_in[20];

    float* ws   = (float*)d_ws;
    float* h    = ws;                      // 4096*256   = 1M floats
    float* qb   = h    + (1 << 20);        // qb/kb/vb: [B,H,L,32] each 1M
    float* kb   = qb   + (1 << 20);
    float* vb   = kb   + (1 << 20);
    float* ctxb = vb   + (1 << 20);
    float* ffb  = ctxb + (1 << 20);        // 4096*1024 = 4M

    k_embed<<<ROWS, 256, 0, stream>>>(x, emb_w, emb_b, h);

    for (int l = 0; l < 2; ++l) {
        const float* wql = wq + (size_t)l * 65536;  const float* bql = bq + l * 256;
        const float* wkl = wk + (size_t)l * 65536;  const float* bkl = bk + l * 256;
        const float* wvl = wv + (size_t)l * 65536;  const float* bvl = bv + l * 256;
        const float* wol = wo + (size_t)l * 65536;  const float* bol = bo + l * 256;

        dim3 gq(64, 4, 3);
        k_qkv<<<gq, 256, 0, stream>>>(h, wql, wkl, wvl, bql, bkl, bvl, qb);

        k_attn<<<NHEAD * BATCH * 512, 256, 0, stream>>>(qb, kb, vb, ctxb);

        // wo: split-K (128 x 2) -> partials in qb, kb (free after attn)
        dim3 gsk(64, 4, 2);
        k_gemm_sk<<<gsk, 256, 0, stream>>>(ctxb, 256, wol, bol, qb, 256, 128);
        k_addln2<<<ROWS, 64, 0, stream>>>(h, qb, kb, ln1_g + l * 256, ln1_b + l * 256);

        dim3 gf1(64, 16);
        k_ff1<<<gf1, 256, 0, stream>>>(h, ff1_w + (size_t)l * 262144, ff1_b + l * 1024, ffb);

        // ff2: split-K (512 x 2) -> partials in qb, kb
        k_gemm_sk<<<gsk, 256, 0, stream>>>(ffb, 1024, ff2_w + (size_t)l * 262144,
                                           ff2_b + l * 256, qb, 256, 512);
        k_addln2<<<ROWS, 64, 0, stream>>>(h, qb, kb, ln2_g + l * 256, ln2_b + l * 256);
    }

    k_dec<<<ROWS, 64, 0, stream>>>(h, dec_w, dec_b, (float*)d_out);
}

// Round 17
// 767.620 us; speedup vs baseline: 2.2169x; 2.2169x over previous
//
#include <hip/hip_runtime.h>
#include <math.h>

#define D_MODEL 256
#define NHEAD   8
#define D_K     32
#define LSEQ    2048
#define BATCH   2
#define ROWS    (BATCH * LSEQ)   // 4096
#define D_FF    1024
#define UTOP    38
#define CAP     128

// ---------------------------------------------------------------------------
// Embedding + positional encoding
// ---------------------------------------------------------------------------
__global__ __launch_bounds__(256) void k_embed(const float* __restrict__ x,
                                               const float* __restrict__ w,
                                               const float* __restrict__ b,
                                               float* __restrict__ h) {
    int row = blockIdx.x;           // b*L + l
    int l   = row & (LSEQ - 1);
    int d   = threadIdx.x;
    __shared__ float xs[32];
    if (d < 32) xs[d] = x[row * 32 + d];
    __syncthreads();
    float acc = 0.f;
#pragma unroll
    for (int i = 0; i < 32; ++i) acc += xs[i] * w[i * D_MODEL + d];
    acc = (acc + b[d]) * 16.0f;     // sqrt(256)
    int m = d >> 1;
    float div = expf(-(float)(2 * m) * (9.210340371976184f / 256.0f)); // ln(1e4)/256
    float ang = (float)l * div;
    float pe = (d & 1) ? cosf(ang) : sinf(ang);
    h[row * D_MODEL + d] = acc + pe;
}

// ---------------------------------------------------------------------------
// Shared fp32 tiled GEMM body: C[64x64 tile] = A[M,K(lda)] @ W[K,N] (+ bias)
// MODE 0: plain   MODE 1: relu   MODE 2: scatter to q/k/v layout [B,H,L,32]
// ---------------------------------------------------------------------------
template <int MODE>
__device__ __forceinline__ void gemm_body(const float* __restrict__ A, int lda,
                                          const float* __restrict__ W, int N,
                                          const float* __restrict__ bias, bool doBias,
                                          float* __restrict__ C, int K,
                                          int m0, int n0) {
    __shared__ float As[16][68];
    __shared__ float Ws[16][68];
    const int t  = threadIdx.x;
    const int tx = t & 15, ty = t >> 4;
    float acc[4][4] = {};
    for (int k0 = 0; k0 < K; k0 += 16) {
        {
            int mr = t >> 2, kc = (t & 3) * 4;
            float4 av = *(const float4*)&A[(size_t)(m0 + mr) * lda + k0 + kc];
            As[kc + 0][mr] = av.x; As[kc + 1][mr] = av.y;
            As[kc + 2][mr] = av.z; As[kc + 3][mr] = av.w;
            int kr = t >> 4, nc = (t & 15) * 4;
            *(float4*)&Ws[kr][nc] = *(const float4*)&W[(size_t)(k0 + kr) * N + n0 + nc];
        }
        __syncthreads();
#pragma unroll
        for (int k = 0; k < 16; ++k) {
            float4 a4 = *(const float4*)&As[k][ty * 4];
            float4 w4 = *(const float4*)&Ws[k][tx * 4];
            float av[4] = {a4.x, a4.y, a4.z, a4.w};
            float wv[4] = {w4.x, w4.y, w4.z, w4.w};
#pragma unroll
            for (int i = 0; i < 4; ++i)
#pragma unroll
                for (int j = 0; j < 4; ++j) acc[i][j] += av[i] * wv[j];
        }
        __syncthreads();
    }
#pragma unroll
    for (int i = 0; i < 4; ++i) {
        int row = m0 + ty * 4 + i;
#pragma unroll
        for (int j = 0; j < 4; ++j) {
            int col = n0 + tx * 4 + j;
            float v = acc[i][j];
            if (doBias) v += bias[col];
            if (MODE == 1) v = fmaxf(v, 0.f);
            if (MODE == 2) {
                int bb = row >> 11, ll = row & (LSEQ - 1);
                int hh = col >> 5, dd = col & 31;
                C[(((size_t)(bb * NHEAD + hh) * LSEQ) + ll) * D_K + dd] = v;
            } else {
                C[(size_t)row * N + col] = v;
            }
        }
    }
}

// QKV fused: blockIdx.z selects {wq,wk,wv}; scatters to [B,H,L,32] at out+z*1M.
__global__ __launch_bounds__(256) void k_qkv(const float* __restrict__ A,
                                             const float* __restrict__ wq,
                                             const float* __restrict__ wk,
                                             const float* __restrict__ wv,
                                             const float* __restrict__ bq,
                                             const float* __restrict__ bk,
                                             const float* __restrict__ bv,
                                             float* __restrict__ out) {
    int z = blockIdx.z;
    const float* W = z == 0 ? wq : (z == 1 ? wk : wv);
    const float* B = z == 0 ? bq : (z == 1 ? bk : bv);
    gemm_body<2>(A, 256, W, 256, B, true, out + (size_t)z * (1 << 20), 256,
                 blockIdx.x * 64, blockIdx.y * 64);
}

// split-K GEMM: blockIdx.z = K-half; partial z to Cbase + z*1M; bias on z=0 only.
__global__ __launch_bounds__(256) void k_gemm_sk(const float* __restrict__ A, int lda,
                                                 const float* __restrict__ W,
                                                 const float* __restrict__ bias,
                                                 float* __restrict__ Cbase,
                                                 int N, int Ksub) {
    int z = blockIdx.z;
    gemm_body<0>(A + (size_t)z * Ksub, lda, W + (size_t)z * Ksub * N, N, bias, z == 0,
                 Cbase + (size_t)z * (1 << 20), Ksub, blockIdx.x * 64, blockIdx.y * 64);
}

// ff1: relu GEMM, N=1024
__global__ __launch_bounds__(256) void k_ff1(const float* __restrict__ A,
                                             const float* __restrict__ W,
                                             const float* __restrict__ bias,
                                             float* __restrict__ C) {
    gemm_body<1>(A, 256, W, 1024, bias, true, C, 256, blockIdx.x * 64, blockIdx.y * 64);
}

// ---------------------------------------------------------------------------
// Fused ProbSparse attention — R14 structure (best: 308 us) + batched-gather
// epilogue. Single pass, d-split, chunk-major LDS, triple-buffer vmcnt(2),
// pivot bitonic, register candidate push, bitonic threshold (64-wide fast
// path when cnt<=64), softmax + PV with 8-wide independent gather batches
// (breaks the serialized ~400-cyc per-iteration gather chain).
// __launch_bounds__(256,3): ~135 live regs needs 170 budget (R10/R16 rule).
// ---------------------------------------------------------------------------
__device__ __forceinline__ unsigned int sortkey(float f) {
    unsigned int u = __float_as_uint(f);
    return (u & 0x80000000u) ? ~u : (u | 0x80000000u);
}
__device__ __forceinline__ float key2f(unsigned int u) {
    unsigned int b = (u & 0x80000000u) ? (u ^ 0x80000000u) : ~u;
    return __uint_as_float(b);
}
__device__ __forceinline__ void gload_lds16(const float* src, float* ldsDst) {
    __builtin_amdgcn_global_load_lds(
        (const __attribute__((address_space(1))) unsigned int*)src,
        (__attribute__((address_space(3))) unsigned int*)ldsDst,
        16, 0, 0);
}

__global__ __launch_bounds__(256, 3) void k_attn(const float* __restrict__ Q,
                                                 const float* __restrict__ Kt,
                                                 const float* __restrict__ Vt,
                                                 float* __restrict__ ctxb) {
    __shared__ float          Kl[3][2048];      // 24 KB  K tile triple-buffer
    __shared__ unsigned int   lvk[4][2][CAP];   // 4 KB   candidate keys
    __shared__ unsigned short lix[4][2][CAP];   // 2 KB   candidate indices
    __shared__ int            lcnt[4][2];

    const int tid   = threadIdx.x;
    const int lane  = tid & 63;
    const int wid   = tid >> 6;
    // XCD swizzle: grid 4096 = 8 XCDs x 512 (bijective).
    const int lbid  = (blockIdx.x & 7) * 512 + (blockIdx.x >> 3);
    const int bh    = lbid >> 8;                // 16 bh x 256 chunks
    const int chunk = lbid & 255;
    const int row0  = chunk * 8 + wid * 2;      // 2 rows per wave
    const int b     = bh >> 3, hh = bh & 7;
    const int h     = lane >> 5;                // d-half owned by this lane
    const int p     = lane & 31;

    const float* Kb = Kt + (size_t)bh * LSEQ * D_K;
    const float* Vb = Vt + (size_t)bh * LSEQ * D_K;
    const float* qp = Q + ((size_t)bh * LSEQ + row0) * D_K;

    const float scale = 0.17677669529663687f;   // 1/sqrt(32)
    float q0[16], q1[16];
#pragma unroll
    for (int i = 0; i < 16; ++i) {
        q0[i] = qp[h * 16 + i] * scale;
        q1[i] = qp[32 + h * 16 + i] * scale;
    }

    // Stage tile T: wave wid stages granules g = wid*2+{0,1} (g in 0..7).
    // Granule g holds dim-chunk (g&3) of keys 2p + (g>>2), half h, for all p.
#define STAGE(T, SLOT)                                                          \
    {                                                                           \
        const int g0_ = wid * 2, g1_ = wid * 2 + 1;                             \
        gload_lds16(Kb + (size_t)(T) * 2048 + (2 * p + (g0_ >> 2)) * 32         \
                        + h * 16 + (g0_ & 3) * 4, &Kl[SLOT][g0_ * 256]);        \
        gload_lds16(Kb + (size_t)(T) * 2048 + (2 * p + (g1_ >> 2)) * 32         \
                        + h * 16 + (g1_ & 3) * 4, &Kl[SLOT][g1_ * 256]);        \
    }

    // ---- single pass: half-dots -> combine -> registers, lane-max ------
    unsigned int k0[32], k1[32];
    unsigned int lm0 = 0u, lm1 = 0u;

    STAGE(0, 0)
    STAGE(1, 1)
    asm volatile("s_waitcnt vmcnt(2)" ::: "memory");
    __builtin_amdgcn_s_barrier();

#pragma unroll
    for (int t = 0; t < 32; ++t) {
        const int slot = t % 3;               // literal under full unroll
        if (t < 30) STAGE(t + 2, (t + 2) % 3)
        float a0 = 0.f, a1 = 0.f, e0 = 0.f, e1 = 0.f;
#pragma unroll
        for (int c = 0; c < 4; ++c) {
            float4 kva = *(const float4*)&Kl[slot][c * 256 + lane * 4];        // key 2p
            float4 kvb = *(const float4*)&Kl[slot][(4 + c) * 256 + lane * 4];  // key 2p+1
            a0 += q0[c*4+0]*kva.x + q0[c*4+1]*kva.y + q0[c*4+2]*kva.z + q0[c*4+3]*kva.w;
            a1 += q1[c*4+0]*kva.x + q1[c*4+1]*kva.y + q1[c*4+2]*kva.z + q1[c*4+3]*kva.w;
            e0 += q0[c*4+0]*kvb.x + q0[c*4+1]*kvb.y + q0[c*4+2]*kvb.z + q0[c*4+3]*kvb.w;
            e1 += q1[c*4+0]*kvb.x + q1[c*4+1]*kvb.y + q1[c*4+2]*kvb.z + q1[c*4+3]*kvb.w;
        }
        float fA0 = a0 + __shfl_xor(a0, 32);
        float fB0 = e0 + __shfl_xor(e0, 32);
        float fA1 = a1 + __shfl_xor(a1, 32);
        float fB1 = e1 + __shfl_xor(e1, 32);
        k0[t] = sortkey(h ? fB0 : fA0);       // lane keeps key 2p+h
        k1[t] = sortkey(h ? fB1 : fA1);
        if (k0[t] > lm0) lm0 = k0[t];
        if (k1[t] > lm1) lm1 = k1[t];
        if (t < 31) {
            if (t < 30) asm volatile("s_waitcnt vmcnt(2)" ::: "memory");
            else        asm volatile("s_waitcnt vmcnt(0)" ::: "memory");
            __builtin_amdgcn_s_barrier();
        }
    }

    // ---- pivot per row: bitonic-sort 64 lane-maxes, broadcast via shfl --
    unsigned int Tpiv[2];
    float        rmaxf[2];
#pragma unroll
    for (int r = 0; r < 2; ++r) {
        unsigned int v = r ? lm1 : lm0;
#pragma unroll
        for (int k = 2; k <= 64; k <<= 1) {
#pragma unroll
            for (int j = k >> 1; j >= 1; j >>= 1) {
                unsigned int pv = (unsigned int)__shfl_xor((int)v, j);
                bool lower = ((lane & j) == 0);
                bool up    = ((lane & k) == 0);
                unsigned int mn = v < pv ? v : pv;
                unsigned int mx = v < pv ? pv : v;
                v = (lower == up) ? mn : mx;
            }
        }
        Tpiv[r]  = (unsigned int)__shfl((int)v, 26);  // 38th-largest lane-max
        rmaxf[r] = key2f((unsigned int)__shfl((int)v, 63));
    }
    if (lane < 2) lcnt[wid][lane] = 0;

    // ---- push candidates >= pivot from registers -----------------------
#pragma unroll
    for (int j = 0; j < 32; ++j) {
        if (k0[j] >= Tpiv[0]) {
            int s = atomicAdd(&lcnt[wid][0], 1);
            if (s < CAP) { lvk[wid][0][s] = k0[j]; lix[wid][0][s] = (unsigned short)(j * 64 + 2 * p + h); }
        }
        if (k1[j] >= Tpiv[1]) {
            int s = atomicAdd(&lcnt[wid][1], 1);
            if (s < CAP) { lvk[wid][1][s] = k1[j]; lix[wid][1][s] = (unsigned short)(j * 64 + 2 * p + h); }
        }
    }

    // ---- per-row: exact threshold (bitonic), softmax, batched PV -------
#pragma unroll
    for (int r = 0; r < 2; ++r) {
        int cnt = lcnt[wid][r]; if (cnt > CAP) cnt = CAP;

        unsigned int thrkey;
        if (cnt <= 64) {
            // 64-wide bitonic on v0 only (common case, E[cnt]~56)
            unsigned int v0 = (lane < cnt) ? lvk[wid][r][lane] : 0u;
#pragma unroll
            for (int k = 2; k <= 64; k <<= 1) {
#pragma unroll
                for (int j = k >> 1; j >= 1; j >>= 1) {
                    unsigned int pv = (unsigned int)__shfl_xor((int)v0, j);
                    bool lower = ((lane & j) == 0);
                    bool up    = ((lane & k) == 0);
                    unsigned int mn = v0 < pv ? v0 : pv;
                    unsigned int mx = v0 < pv ? pv : v0;
                    v0 = (lower == up) ? mn : mx;
                }
            }
            thrkey = (unsigned int)__shfl((int)v0, 26);   // ascending idx 64-38
        } else {
            unsigned int v0 = (lane < cnt)      ? lvk[wid][r][lane]      : 0u;
            unsigned int v1 = (64 + lane < cnt) ? lvk[wid][r][64 + lane] : 0u;
#pragma unroll
            for (int k = 2; k <= 128; k <<= 1) {
#pragma unroll
                for (int j = k >> 1; j >= 1; j >>= 1) {
                    if (j >= 64) {
                        bool up0 = ((lane & k) == 0);
                        unsigned int mn = v0 < v1 ? v0 : v1;
                        unsigned int mx = v0 < v1 ? v1 : v0;
                        v0 = up0 ? mn : mx;
                        v1 = up0 ? mx : mn;
                    } else {
                        unsigned int pp0 = (unsigned int)__shfl_xor((int)v0, j);
                        unsigned int pp1 = (unsigned int)__shfl_xor((int)v1, j);
                        bool lower = ((lane & j) == 0);
                        bool up0 = (((lane) & k) == 0);
                        bool up1 = (((64 + lane) & k) == 0);
                        v0 = (lower == up0) ? (v0 < pp0 ? v0 : pp0) : (v0 < pp0 ? pp0 : v0);
                        v1 = (lower == up1) ? (v1 < pp1 ? v1 : pp1) : (v1 < pp1 ? pp1 : v1);
                    }
                }
            }
            thrkey = (unsigned int)__shfl((int)v1, 26);   // ascending idx 90
        }

        float psum = 0.f;
        for (int i = lane; i < cnt; i += 64) {
            unsigned int key = lvk[wid][r][i];
            if (key >= thrkey) psum += __expf(key2f(key) - rmaxf[r]);
        }
#pragma unroll
        for (int off = 32; off >= 1; off >>= 1) psum += __shfl_xor(psum, off);
        float inv = 1.0f / psum;

        // PV: 8-wide batches of independent gathers (breaks serial chain)
        float acc = 0.f;
        for (int i0 = h; i0 < cnt; i0 += 16) {
            float wgt0, wgt1, wgt2, wgt3, wgt4, wgt5, wgt6, wgt7;
            int   ix0, ix1, ix2, ix3, ix4, ix5, ix6, ix7;
#define PREP(U, W, X)                                                           \
            {                                                                   \
                int i = i0 + 2 * (U);                                           \
                bool ok = i < cnt;                                              \
                unsigned int key = ok ? lvk[wid][r][i] : 0u;                    \
                W = (ok && key >= thrkey) ? __expf(key2f(key) - rmaxf[r]) : 0.f;\
                X = ok ? (int)lix[wid][r][i] : 0;                               \
            }
            PREP(0, wgt0, ix0) PREP(1, wgt1, ix1) PREP(2, wgt2, ix2) PREP(3, wgt3, ix3)
            PREP(4, wgt4, ix4) PREP(5, wgt5, ix5) PREP(6, wgt6, ix6) PREP(7, wgt7, ix7)
#undef PREP
            acc += wgt0 * Vb[(size_t)ix0 * D_K + p];
            acc += wgt1 * Vb[(size_t)ix1 * D_K + p];
            acc += wgt2 * Vb[(size_t)ix2 * D_K + p];
            acc += wgt3 * Vb[(size_t)ix3 * D_K + p];
            acc += wgt4 * Vb[(size_t)ix4 * D_K + p];
            acc += wgt5 * Vb[(size_t)ix5 * D_K + p];
            acc += wgt6 * Vb[(size_t)ix6 * D_K + p];
            acc += wgt7 * Vb[(size_t)ix7 * D_K + p];
        }
        acc += __shfl_xor(acc, 32);
        if (lane < 32)
            ctxb[((size_t)(b * LSEQ) + row0 + r) * D_MODEL + hh * D_K + p] = acc * inv;
    }
}

// ---------------------------------------------------------------------------
// Residual add (two partials) + LayerNorm over 256, in place into h.
// ---------------------------------------------------------------------------
__global__ __launch_bounds__(64) void k_addln2(float* __restrict__ h,
                                               const float* __restrict__ a1,
                                               const float* __restrict__ a2,
                                               const float* __restrict__ g,
                                               const float* __restrict__ bb) {
    int row = blockIdx.x, lane = threadIdx.x;
    float4 hv = *(const float4*)&h[(size_t)row * D_MODEL + lane * 4];
    float4 v1 = *(const float4*)&a1[(size_t)row * D_MODEL + lane * 4];
    float4 v2 = *(const float4*)&a2[(size_t)row * D_MODEL + lane * 4];
    float x0 = hv.x + v1.x + v2.x, x1 = hv.y + v1.y + v2.y;
    float x2 = hv.z + v1.z + v2.z, x3 = hv.w + v1.w + v2.w;
    float s = x0 + x1 + x2 + x3;
#pragma unroll
    for (int off = 32; off >= 1; off >>= 1) s += __shfl_xor(s, off);
    float mean = s * (1.0f / 256.0f);
    float d0 = x0 - mean, d1 = x1 - mean, d2 = x2 - mean, d3 = x3 - mean;
    float vs = d0 * d0 + d1 * d1 + d2 * d2 + d3 * d3;
#pragma unroll
    for (int off = 32; off >= 1; off >>= 1) vs += __shfl_xor(vs, off);
    float inv = rsqrtf(vs * (1.0f / 256.0f) + 1e-5f);
    float4 gv = *(const float4*)&g[lane * 4];
    float4 bv = *(const float4*)&bb[lane * 4];
    float4 o;
    o.x = d0 * inv * gv.x + bv.x;
    o.y = d1 * inv * gv.y + bv.y;
    o.z = d2 * inv * gv.z + bv.z;
    o.w = d3 * inv * gv.w + bv.w;
    *(float4*)&h[(size_t)row * D_MODEL + lane * 4] = o;
}

// ---------------------------------------------------------------------------
// Decoder head
// ---------------------------------------------------------------------------
__global__ __launch_bounds__(64) void k_dec(const float* __restrict__ h,
                                            const float* __restrict__ w,
                                            const float* __restrict__ b,
                                            float* __restrict__ out) {
    int row = blockIdx.x, lane = threadIdx.x;
    int c = lane & 7, part = lane >> 3;   // 8 parts x 32 dims
    float acc = 0.f;
    int d0 = part * 32;
#pragma unroll
    for (int dd = 0; dd < 32; ++dd) acc += h[(size_t)row * D_MODEL + d0 + dd] * w[(d0 + dd) * 8 + c];
    acc += __shfl_xor(acc, 8);
    acc += __shfl_xor(acc, 16);
    acc += __shfl_xor(acc, 32);
    if (lane < 8) out[(size_t)row * 8 + c] = acc + b[c];
}

// ---------------------------------------------------------------------------
extern "C" void kernel_launch(void* const* d_in, const int* in_sizes, int n_in,
                              void* d_out, int out_size, void* d_ws, size_t ws_size,
                              hipStream_t stream) {
    const float* x     = (const float*)d_in[0];
    const float* emb_w = (const float*)d_in[1];
    const float* emb_b = (const float*)d_in[2];
    const float* wq    = (const float*)d_in[3];
    const float* bq    = (const float*)d_in[4];
    const float* wk    = (const float*)d_in[5];
    const float* bk    = (const float*)d_in[6];
    const float* wv    = (const float*)d_in[7];
    const float* bv    = (const float*)d_in[8];
    const float* wo    = (const float*)d_in[9];
    const float* bo    = (const float*)d_in[10];
    const float* ln1_g = (const float*)d_in[11];
    const float* ln1_b = (const float*)d_in[12];
    const float* ln2_g = (const float*)d_in[13];
    const float* ln2_b = (const float*)d_in[14];
    const float* ff1_w = (const float*)d_in[15];
    const float* ff1_b = (const float*)d_in[16];
    const float* ff2_w = (const float*)d_in[17];
    const float* ff2_b = (const float*)d_in[18];
    const float* dec_w = (const float*)d_in[19];
    const float* dec_b = (const float*)d_in[20];

    float* ws   = (float*)d_ws;
    float* h    = ws;                      // 4096*256   = 1M floats
    float* qb   = h    + (1 << 20);        // qb/kb/vb: [B,H,L,32] each 1M
    float* kb   = qb   + (1 << 20);
    float* vb   = kb   + (1 << 20);
    float* ctxb = vb   + (1 << 20);
    float* ffb  = ctxb + (1 << 20);        // 4096*1024 = 4M

    k_embed<<<ROWS, 256, 0, stream>>>(x, emb_w, emb_b, h);

    for (int l = 0; l < 2; ++l) {
        const float* wql = wq + (size_t)l * 65536;  const float* bql = bq + l * 256;
        const float* wkl = wk + (size_t)l * 65536;  const float* bkl = bk + l * 256;
        const float* wvl = wv + (size_t)l * 65536;  const float* bvl = bv + l * 256;
        const float* wol = wo + (size_t)l * 65536;  const float* bol = bo + l * 256;

        dim3 gq(64, 4, 3);
        k_qkv<<<gq, 256, 0, stream>>>(h, wql, wkl, wvl, bql, bkl, bvl, qb);

        k_attn<<<NHEAD * BATCH * 256, 256, 0, stream>>>(qb, kb, vb, ctxb);

        // wo: split-K (128 x 2) -> partials in qb, kb (free after attn)
        dim3 gsk(64, 4, 2);
        k_gemm_sk<<<gsk, 256, 0, stream>>>(ctxb, 256, wol, bol, qb, 256, 128);
        k_addln2<<<ROWS, 64, 0, stream>>>(h, qb, kb, ln1_g + l * 256, ln1_b + l * 256);

        dim3 gf1(64, 16);
        k_ff1<<<gf1, 256, 0, stream>>>(h, ff1_w + (size_t)l * 262144, ff1_b + l * 1024, ffb);

        // ff2: split-K (512 x 2) -> partials in qb, kb
        k_gemm_sk<<<gsk, 256, 0, stream>>>(ffb, 1024, ff2_w + (size_t)l * 262144,
                                           ff2_b + l * 256, qb, 256, 512);
        k_addln2<<<ROWS, 64, 0, stream>>>(h, qb, kb, ln2_g + l * 256, ln2_b + l * 256);
    }

    k_dec<<<ROWS, 64, 0, stream>>>(h, dec_w, dec_b, (float*)d_out);
}

// Round 18
// 750.158 us; speedup vs baseline: 2.2685x; 1.0233x over previous
//
#include <hip/hip_runtime.h>
#include <math.h>

#define D_MODEL 256
#define NHEAD   8
#define D_K     32
#define LSEQ    2048
#define BATCH   2
#define ROWS    (BATCH * LSEQ)   // 4096
#define D_FF    1024
#define UTOP    38
#define CAP     128

// ---------------------------------------------------------------------------
// Embedding + positional encoding
// ---------------------------------------------------------------------------
__global__ __launch_bounds__(256) void k_embed(const float* __restrict__ x,
                                               const float* __restrict__ w,
                                               const float* __restrict__ b,
                                               float* __restrict__ h) {
    int row = blockIdx.x;           // b*L + l
    int l   = row & (LSEQ - 1);
    int d   = threadIdx.x;
    __shared__ float xs[32];
    if (d < 32) xs[d] = x[row * 32 + d];
    __syncthreads();
    float acc = 0.f;
#pragma unroll
    for (int i = 0; i < 32; ++i) acc += xs[i] * w[i * D_MODEL + d];
    acc = (acc + b[d]) * 16.0f;     // sqrt(256)
    int m = d >> 1;
    float div = expf(-(float)(2 * m) * (9.210340371976184f / 256.0f)); // ln(1e4)/256
    float ang = (float)l * div;
    float pe = (d & 1) ? cosf(ang) : sinf(ang);
    h[row * D_MODEL + d] = acc + pe;
}

// ---------------------------------------------------------------------------
// Shared fp32 tiled GEMM body: C[64x64 tile] = A[M,K(lda)] @ W[K,N] (+ bias)
// MODE 0: plain   MODE 1: relu   MODE 2: scatter to q/k/v layout [B,H,L,32]
// ---------------------------------------------------------------------------
template <int MODE>
__device__ __forceinline__ void gemm_body(const float* __restrict__ A, int lda,
                                          const float* __restrict__ W, int N,
                                          const float* __restrict__ bias, bool doBias,
                                          float* __restrict__ C, int K,
                                          int m0, int n0) {
    __shared__ float As[16][68];
    __shared__ float Ws[16][68];
    const int t  = threadIdx.x;
    const int tx = t & 15, ty = t >> 4;
    float acc[4][4] = {};
    for (int k0 = 0; k0 < K; k0 += 16) {
        {
            int mr = t >> 2, kc = (t & 3) * 4;
            float4 av = *(const float4*)&A[(size_t)(m0 + mr) * lda + k0 + kc];
            As[kc + 0][mr] = av.x; As[kc + 1][mr] = av.y;
            As[kc + 2][mr] = av.z; As[kc + 3][mr] = av.w;
            int kr = t >> 4, nc = (t & 15) * 4;
            *(float4*)&Ws[kr][nc] = *(const float4*)&W[(size_t)(k0 + kr) * N + n0 + nc];
        }
        __syncthreads();
#pragma unroll
        for (int k = 0; k < 16; ++k) {
            float4 a4 = *(const float4*)&As[k][ty * 4];
            float4 w4 = *(const float4*)&Ws[k][tx * 4];
            float av[4] = {a4.x, a4.y, a4.z, a4.w};
            float wv[4] = {w4.x, w4.y, w4.z, w4.w};
#pragma unroll
            for (int i = 0; i < 4; ++i)
#pragma unroll
                for (int j = 0; j < 4; ++j) acc[i][j] += av[i] * wv[j];
        }
        __syncthreads();
    }
#pragma unroll
    for (int i = 0; i < 4; ++i) {
        int row = m0 + ty * 4 + i;
#pragma unroll
        for (int j = 0; j < 4; ++j) {
            int col = n0 + tx * 4 + j;
            float v = acc[i][j];
            if (doBias) v += bias[col];
            if (MODE == 1) v = fmaxf(v, 0.f);
            if (MODE == 2) {
                int bb = row >> 11, ll = row & (LSEQ - 1);
                int hh = col >> 5, dd = col & 31;
                C[(((size_t)(bb * NHEAD + hh) * LSEQ) + ll) * D_K + dd] = v;
            } else {
                C[(size_t)row * N + col] = v;
            }
        }
    }
}

// QKV fused: blockIdx.z selects {wq,wk,wv}; scatters to [B,H,L,32] at out+z*1M.
__global__ __launch_bounds__(256) void k_qkv(const float* __restrict__ A,
                                             const float* __restrict__ wq,
                                             const float* __restrict__ wk,
                                             const float* __restrict__ wv,
                                             const float* __restrict__ bq,
                                             const float* __restrict__ bk,
                                             const float* __restrict__ bv,
                                             float* __restrict__ out) {
    int z = blockIdx.z;
    const float* W = z == 0 ? wq : (z == 1 ? wk : wv);
    const float* B = z == 0 ? bq : (z == 1 ? bk : bv);
    gemm_body<2>(A, 256, W, 256, B, true, out + (size_t)z * (1 << 20), 256,
                 blockIdx.x * 64, blockIdx.y * 64);
}

// split-K GEMM: blockIdx.z = K-half; partial z to Cbase + z*1M; bias on z=0 only.
__global__ __launch_bounds__(256) void k_gemm_sk(const float* __restrict__ A, int lda,
                                                 const float* __restrict__ W,
                                                 const float* __restrict__ bias,
                                                 float* __restrict__ Cbase,
                                                 int N, int Ksub) {
    int z = blockIdx.z;
    gemm_body<0>(A + (size_t)z * Ksub, lda, W + (size_t)z * Ksub * N, N, bias, z == 0,
                 Cbase + (size_t)z * (1 << 20), Ksub, blockIdx.x * 64, blockIdx.y * 64);
}

// ff1: relu GEMM, N=1024
__global__ __launch_bounds__(256) void k_ff1(const float* __restrict__ A,
                                             const float* __restrict__ W,
                                             const float* __restrict__ bias,
                                             float* __restrict__ C) {
    gemm_body<1>(A, 256, W, 1024, bias, true, C, 256, blockIdx.x * 64, blockIdx.y * 64);
}

// ---------------------------------------------------------------------------
// Fused ProbSparse attention — R17 winner + 5-slot deep staging pipeline.
// Phase t: STAGE(t+4) -> vmcnt(8) (tile t's loads 4 issues old) -> compute
// -> s_barrier. Latency budget ~4 phases (~800+ cyc) covers queued-L2.
// Single pass, d-split, chunk-major LDS, pivot bitonic, register candidate
// push, bitonic threshold (64-wide fast path), batched 8-wide PV gather.
// __launch_bounds__(256,3): ~135 live regs needs 170 budget.
// ---------------------------------------------------------------------------
__device__ __forceinline__ unsigned int sortkey(float f) {
    unsigned int u = __float_as_uint(f);
    return (u & 0x80000000u) ? ~u : (u | 0x80000000u);
}
__device__ __forceinline__ float key2f(unsigned int u) {
    unsigned int b = (u & 0x80000000u) ? (u ^ 0x80000000u) : ~u;
    return __uint_as_float(b);
}
__device__ __forceinline__ void gload_lds16(const float* src, float* ldsDst) {
    __builtin_amdgcn_global_load_lds(
        (const __attribute__((address_space(1))) unsigned int*)src,
        (__attribute__((address_space(3))) unsigned int*)ldsDst,
        16, 0, 0);
}

__global__ __launch_bounds__(256, 3) void k_attn(const float* __restrict__ Q,
                                                 const float* __restrict__ Kt,
                                                 const float* __restrict__ Vt,
                                                 float* __restrict__ ctxb) {
    __shared__ float          Kl[5][2048];      // 40 KB  K tile 5-slot pipeline
    __shared__ unsigned int   lvk[4][2][CAP];   // 4 KB   candidate keys
    __shared__ unsigned short lix[4][2][CAP];   // 2 KB   candidate indices
    __shared__ int            lcnt[4][2];

    const int tid   = threadIdx.x;
    const int lane  = tid & 63;
    const int wid   = tid >> 6;
    // XCD swizzle: grid 4096 = 8 XCDs x 512 (bijective).
    const int lbid  = (blockIdx.x & 7) * 512 + (blockIdx.x >> 3);
    const int bh    = lbid >> 8;                // 16 bh x 256 chunks
    const int chunk = lbid & 255;
    const int row0  = chunk * 8 + wid * 2;      // 2 rows per wave
    const int b     = bh >> 3, hh = bh & 7;
    const int h     = lane >> 5;                // d-half owned by this lane
    const int p     = lane & 31;

    const float* Kb = Kt + (size_t)bh * LSEQ * D_K;
    const float* Vb = Vt + (size_t)bh * LSEQ * D_K;
    const float* qp = Q + ((size_t)bh * LSEQ + row0) * D_K;

    const float scale = 0.17677669529663687f;   // 1/sqrt(32)
    float q0[16], q1[16];
#pragma unroll
    for (int i = 0; i < 16; ++i) {
        q0[i] = qp[h * 16 + i] * scale;
        q1[i] = qp[32 + h * 16 + i] * scale;
    }

    // Stage tile T: wave wid stages granules g = wid*2+{0,1} (g in 0..7).
    // Granule g holds dim-chunk (g&3) of keys 2p + (g>>2), half h, for all p.
#define STAGE(T, SLOT)                                                          \
    {                                                                           \
        const int g0_ = wid * 2, g1_ = wid * 2 + 1;                             \
        gload_lds16(Kb + (size_t)(T) * 2048 + (2 * p + (g0_ >> 2)) * 32         \
                        + h * 16 + (g0_ & 3) * 4, &Kl[SLOT][g0_ * 256]);        \
        gload_lds16(Kb + (size_t)(T) * 2048 + (2 * p + (g1_ >> 2)) * 32         \
                        + h * 16 + (g1_ & 3) * 4, &Kl[SLOT][g1_ * 256]);        \
    }

    // ---- single pass: half-dots -> combine -> registers, lane-max ------
    unsigned int k0[32], k1[32];
    unsigned int lm0 = 0u, lm1 = 0u;

    STAGE(0, 0)
    STAGE(1, 1)
    STAGE(2, 2)
    STAGE(3, 3)

#pragma unroll
    for (int t = 0; t < 32; ++t) {
        const int slot = t % 5;               // literal under full unroll
        if (t + 4 < 32) STAGE(t + 4, (t + 4) % 5)
        // tile t's 2 loads are done when <= 2*(tiles issued after t) remain
        if      (t < 28) asm volatile("s_waitcnt vmcnt(8)" ::: "memory");
        else if (t == 28) asm volatile("s_waitcnt vmcnt(6)" ::: "memory");
        else if (t == 29) asm volatile("s_waitcnt vmcnt(4)" ::: "memory");
        else if (t == 30) asm volatile("s_waitcnt vmcnt(2)" ::: "memory");
        else              asm volatile("s_waitcnt vmcnt(0)" ::: "memory");
        __builtin_amdgcn_s_barrier();

        float a0 = 0.f, a1 = 0.f, e0 = 0.f, e1 = 0.f;
#pragma unroll
        for (int c = 0; c < 4; ++c) {
            float4 kva = *(const float4*)&Kl[slot][c * 256 + lane * 4];        // key 2p
            float4 kvb = *(const float4*)&Kl[slot][(4 + c) * 256 + lane * 4];  // key 2p+1
            a0 += q0[c*4+0]*kva.x + q0[c*4+1]*kva.y + q0[c*4+2]*kva.z + q0[c*4+3]*kva.w;
            a1 += q1[c*4+0]*kva.x + q1[c*4+1]*kva.y + q1[c*4+2]*kva.z + q1[c*4+3]*kva.w;
            e0 += q0[c*4+0]*kvb.x + q0[c*4+1]*kvb.y + q0[c*4+2]*kvb.z + q0[c*4+3]*kvb.w;
            e1 += q1[c*4+0]*kvb.x + q1[c*4+1]*kvb.y + q1[c*4+2]*kvb.z + q1[c*4+3]*kvb.w;
        }
        float fA0 = a0 + __shfl_xor(a0, 32);
        float fB0 = e0 + __shfl_xor(e0, 32);
        float fA1 = a1 + __shfl_xor(a1, 32);
        float fB1 = e1 + __shfl_xor(e1, 32);
        k0[t] = sortkey(h ? fB0 : fA0);       // lane keeps key 2p+h
        k1[t] = sortkey(h ? fB1 : fA1);
        if (k0[t] > lm0) lm0 = k0[t];
        if (k1[t] > lm1) lm1 = k1[t];
        __builtin_amdgcn_s_barrier();         // all waves done with slot before restage
    }

    // ---- pivot per row: bitonic-sort 64 lane-maxes, broadcast via shfl --
    unsigned int Tpiv[2];
    float        rmaxf[2];
#pragma unroll
    for (int r = 0; r < 2; ++r) {
        unsigned int v = r ? lm1 : lm0;
#pragma unroll
        for (int k = 2; k <= 64; k <<= 1) {
#pragma unroll
            for (int j = k >> 1; j >= 1; j >>= 1) {
                unsigned int pv = (unsigned int)__shfl_xor((int)v, j);
                bool lower = ((lane & j) == 0);
                bool up    = ((lane & k) == 0);
                unsigned int mn = v < pv ? v : pv;
                unsigned int mx = v < pv ? pv : v;
                v = (lower == up) ? mn : mx;
            }
        }
        Tpiv[r]  = (unsigned int)__shfl((int)v, 26);  // 38th-largest lane-max
        rmaxf[r] = key2f((unsigned int)__shfl((int)v, 63));
    }
    if (lane < 2) lcnt[wid][lane] = 0;

    // ---- push candidates >= pivot from registers -----------------------
#pragma unroll
    for (int j = 0; j < 32; ++j) {
        if (k0[j] >= Tpiv[0]) {
            int s = atomicAdd(&lcnt[wid][0], 1);
            if (s < CAP) { lvk[wid][0][s] = k0[j]; lix[wid][0][s] = (unsigned short)(j * 64 + 2 * p + h); }
        }
        if (k1[j] >= Tpiv[1]) {
            int s = atomicAdd(&lcnt[wid][1], 1);
            if (s < CAP) { lvk[wid][1][s] = k1[j]; lix[wid][1][s] = (unsigned short)(j * 64 + 2 * p + h); }
        }
    }

    // ---- per-row: exact threshold (bitonic), softmax, batched PV -------
#pragma unroll
    for (int r = 0; r < 2; ++r) {
        int cnt = lcnt[wid][r]; if (cnt > CAP) cnt = CAP;

        unsigned int thrkey;
        if (cnt <= 64) {
            // 64-wide bitonic on v0 only (common case, E[cnt]~56)
            unsigned int v0 = (lane < cnt) ? lvk[wid][r][lane] : 0u;
#pragma unroll
            for (int k = 2; k <= 64; k <<= 1) {
#pragma unroll
                for (int j = k >> 1; j >= 1; j >>= 1) {
                    unsigned int pv = (unsigned int)__shfl_xor((int)v0, j);
                    bool lower = ((lane & j) == 0);
                    bool up    = ((lane & k) == 0);
                    unsigned int mn = v0 < pv ? v0 : pv;
                    unsigned int mx = v0 < pv ? pv : v0;
                    v0 = (lower == up) ? mn : mx;
                }
            }
            thrkey = (unsigned int)__shfl((int)v0, 26);   // ascending idx 64-38
        } else {
            unsigned int v0 = (lane < cnt)      ? lvk[wid][r][lane]      : 0u;
            unsigned int v1 = (64 + lane < cnt) ? lvk[wid][r][64 + lane] : 0u;
#pragma unroll
            for (int k = 2; k <= 128; k <<= 1) {
#pragma unroll
                for (int j = k >> 1; j >= 1; j >>= 1) {
                    if (j >= 64) {
                        bool up0 = ((lane & k) == 0);
                        unsigned int mn = v0 < v1 ? v0 : v1;
                        unsigned int mx = v0 < v1 ? v1 : v0;
                        v0 = up0 ? mn : mx;
                        v1 = up0 ? mx : mn;
                    } else {
                        unsigned int pp0 = (unsigned int)__shfl_xor((int)v0, j);
                        unsigned int pp1 = (unsigned int)__shfl_xor((int)v1, j);
                        bool lower = ((lane & j) == 0);
                        bool up0 = (((lane) & k) == 0);
                        bool up1 = (((64 + lane) & k) == 0);
                        v0 = (lower == up0) ? (v0 < pp0 ? v0 : pp0) : (v0 < pp0 ? pp0 : v0);
                        v1 = (lower == up1) ? (v1 < pp1 ? v1 : pp1) : (v1 < pp1 ? pp1 : v1);
                    }
                }
            }
            thrkey = (unsigned int)__shfl((int)v1, 26);   // ascending idx 90
        }

        float psum = 0.f;
        for (int i = lane; i < cnt; i += 64) {
            unsigned int key = lvk[wid][r][i];
            if (key >= thrkey) psum += __expf(key2f(key) - rmaxf[r]);
        }
#pragma unroll
        for (int off = 32; off >= 1; off >>= 1) psum += __shfl_xor(psum, off);
        float inv = 1.0f / psum;

        // PV: 8-wide batches of independent gathers (breaks serial chain)
        float acc = 0.f;
        for (int i0 = h; i0 < cnt; i0 += 16) {
            float wgt0, wgt1, wgt2, wgt3, wgt4, wgt5, wgt6, wgt7;
            int   ix0, ix1, ix2, ix3, ix4, ix5, ix6, ix7;
#define PREP(U, W, X)                                                           \
            {                                                                   \
                int i = i0 + 2 * (U);                                           \
                bool ok = i < cnt;                                              \
                unsigned int key = ok ? lvk[wid][r][i] : 0u;                    \
                W = (ok && key >= thrkey) ? __expf(key2f(key) - rmaxf[r]) : 0.f;\
                X = ok ? (int)lix[wid][r][i] : 0;                               \
            }
            PREP(0, wgt0, ix0) PREP(1, wgt1, ix1) PREP(2, wgt2, ix2) PREP(3, wgt3, ix3)
            PREP(4, wgt4, ix4) PREP(5, wgt5, ix5) PREP(6, wgt6, ix6) PREP(7, wgt7, ix7)
#undef PREP
            acc += wgt0 * Vb[(size_t)ix0 * D_K + p];
            acc += wgt1 * Vb[(size_t)ix1 * D_K + p];
            acc += wgt2 * Vb[(size_t)ix2 * D_K + p];
            acc += wgt3 * Vb[(size_t)ix3 * D_K + p];
            acc += wgt4 * Vb[(size_t)ix4 * D_K + p];
            acc += wgt5 * Vb[(size_t)ix5 * D_K + p];
            acc += wgt6 * Vb[(size_t)ix6 * D_K + p];
            acc += wgt7 * Vb[(size_t)ix7 * D_K + p];
        }
        acc += __shfl_xor(acc, 32);
        if (lane < 32)
            ctxb[((size_t)(b * LSEQ) + row0 + r) * D_MODEL + hh * D_K + p] = acc * inv;
    }
}

// ---------------------------------------------------------------------------
// Residual add (two partials) + LayerNorm over 256, in place into h.
// ---------------------------------------------------------------------------
__global__ __launch_bounds__(64) void k_addln2(float* __restrict__ h,
                                               const float* __restrict__ a1,
                                               const float* __restrict__ a2,
                                               const float* __restrict__ g,
                                               const float* __restrict__ bb) {
    int row = blockIdx.x, lane = threadIdx.x;
    float4 hv = *(const float4*)&h[(size_t)row * D_MODEL + lane * 4];
    float4 v1 = *(const float4*)&a1[(size_t)row * D_MODEL + lane * 4];
    float4 v2 = *(const float4*)&a2[(size_t)row * D_MODEL + lane * 4];
    float x0 = hv.x + v1.x + v2.x, x1 = hv.y + v1.y + v2.y;
    float x2 = hv.z + v1.z + v2.z, x3 = hv.w + v1.w + v2.w;
    float s = x0 + x1 + x2 + x3;
#pragma unroll
    for (int off = 32; off >= 1; off >>= 1) s += __shfl_xor(s, off);
    float mean = s * (1.0f / 256.0f);
    float d0 = x0 - mean, d1 = x1 - mean, d2 = x2 - mean, d3 = x3 - mean;
    float vs = d0 * d0 + d1 * d1 + d2 * d2 + d3 * d3;
#pragma unroll
    for (int off = 32; off >= 1; off >>= 1) vs += __shfl_xor(vs, off);
    float inv = rsqrtf(vs * (1.0f / 256.0f) + 1e-5f);
    float4 gv = *(const float4*)&g[lane * 4];
    float4 bv = *(const float4*)&bb[lane * 4];
    float4 o;
    o.x = d0 * inv * gv.x + bv.x;
    o.y = d1 * inv * gv.y + bv.y;
    o.z = d2 * inv * gv.z + bv.z;
    o.w = d3 * inv * gv.w + bv.w;
    *(float4*)&h[(size_t)row * D_MODEL + lane * 4] = o;
}

// ---------------------------------------------------------------------------
// Decoder head
// ---------------------------------------------------------------------------
__global__ __launch_bounds__(64) void k_dec(const float* __restrict__ h,
                                            const float* __restrict__ w,
                                            const float* __restrict__ b,
                                            float* __restrict__ out) {
    int row = blockIdx.x, lane = threadIdx.x;
    int c = lane & 7, part = lane >> 3;   // 8 parts x 32 dims
    float acc = 0.f;
    int d0 = part * 32;
#pragma unroll
    for (int dd = 0; dd < 32; ++dd) acc += h[(size_t)row * D_MODEL + d0 + dd] * w[(d0 + dd) * 8 + c];
    acc += __shfl_xor(acc, 8);
    acc += __shfl_xor(acc, 16);
    acc += __shfl_xor(acc, 32);
    if (lane < 8) out[(size_t)row * 8 + c] = acc + b[c];
}

// ---------------------------------------------------------------------------
extern "C" void kernel_launch(void* const* d_in, const int* in_sizes, int n_in,
                              void* d_out, int out_size, void* d_ws, size_t ws_size,
                              hipStream_t stream) {
    const float* x     = (const float*)d_in[0];
    const float* emb_w = (const float*)d_in[1];
    const float* emb_b = (const float*)d_in[2];
    const float* wq    = (const float*)d_in[3];
    const float* bq    = (const float*)d_in[4];
    const float* wk    = (const float*)d_in[5];
    const float* bk    = (const float*)d_in[6];
    const float* wv    = (const float*)d_in[7];
    const float* bv    = (const float*)d_in[8];
    const float* wo    = (const float*)d_in[9];
    const float* bo    = (const float*)d_in[10];
    const float* ln1_g = (const float*)d_in[11];
    const float* ln1_b = (const float*)d_in[12];
    const float* ln2_g = (const float*)d_in[13];
    const float* ln2_b = (const float*)d_in[14];
    const float* ff1_w = (const float*)d_in[15];
    const float* ff1_b = (const float*)d_in[16];
    const float* ff2_w = (const float*)d_in[17];
    const float* ff2_b = (const float*)d_in[18];
    const float* dec_w = (const float*)d_in[19];
    const float* dec_b = (const float*)d_in[20];

    float* ws   = (float*)d_ws;
    float* h    = ws;                      // 4096*256   = 1M floats
    float* qb   = h    + (1 << 20);        // qb/kb/vb: [B,H,L,32] each 1M
    float* kb   = qb   + (1 << 20);
    float* vb   = kb   + (1 << 20);
    float* ctxb = vb   + (1 << 20);
    float* ffb  = ctxb + (1 << 20);        // 4096*1024 = 4M

    k_embed<<<ROWS, 256, 0, stream>>>(x, emb_w, emb_b, h);

    for (int l = 0; l < 2; ++l) {
        const float* wql = wq + (size_t)l * 65536;  const float* bql = bq + l * 256;
        const float* wkl = wk + (size_t)l * 65536;  const float* bkl = bk + l * 256;
        const float* wvl = wv + (size_t)l * 65536;  const float* bvl = bv + l * 256;
        const float* wol = wo + (size_t)l * 65536;  const float* bol = bo + l * 256;

        dim3 gq(64, 4, 3);
        k_qkv<<<gq, 256, 0, stream>>>(h, wql, wkl, wvl, bql, bkl, bvl, qb);

        k_attn<<<NHEAD * BATCH * 256, 256, 0, stream>>>(qb, kb, vb, ctxb);

        // wo: split-K (128 x 2) -> partials in qb, kb (free after attn)
        dim3 gsk(64, 4, 2);
        k_gemm_sk<<<gsk, 256, 0, stream>>>(ctxb, 256, wol, bol, qb, 256, 128);
        k_addln2<<<ROWS, 64, 0, stream>>>(h, qb, kb, ln1_g + l * 256, ln1_b + l * 256);

        dim3 gf1(64, 16);
        k_ff1<<<gf1, 256, 0, stream>>>(h, ff1_w + (size_t)l * 262144, ff1_b + l * 1024, ffb);

        // ff2: split-K (512 x 2) -> partials in qb, kb
        k_gemm_sk<<<gsk, 256, 0, stream>>>(ffb, 1024, ff2_w + (size_t)l * 262144,
                                           ff2_b + l * 256, qb, 256, 512);
        k_addln2<<<ROWS, 64, 0, stream>>>(h, qb, kb, ln2_g + l * 256, ln2_b + l * 256);
    }

    k_dec<<<ROWS, 64, 0, stream>>>(h, dec_w, dec_b, (float*)d_out);
}

// Round 19
// 724.751 us; speedup vs baseline: 2.3480x; 1.0351x over previous
//
#include <hip/hip_runtime.h>
#include <math.h>

#define D_MODEL 256
#define NHEAD   8
#define D_K     32
#define LSEQ    2048
#define BATCH   2
#define ROWS    (BATCH * LSEQ)   // 4096
#define D_FF    1024
#define UTOP    38
#define CAP     128

typedef float v2f __attribute__((ext_vector_type(2)));

// ---------------------------------------------------------------------------
// Embedding + positional encoding
// ---------------------------------------------------------------------------
__global__ __launch_bounds__(256) void k_embed(const float* __restrict__ x,
                                               const float* __restrict__ w,
                                               const float* __restrict__ b,
                                               float* __restrict__ h) {
    int row = blockIdx.x;           // b*L + l
    int l   = row & (LSEQ - 1);
    int d   = threadIdx.x;
    __shared__ float xs[32];
    if (d < 32) xs[d] = x[row * 32 + d];
    __syncthreads();
    float acc = 0.f;
#pragma unroll
    for (int i = 0; i < 32; ++i) acc += xs[i] * w[i * D_MODEL + d];
    acc = (acc + b[d]) * 16.0f;     // sqrt(256)
    int m = d >> 1;
    float div = expf(-(float)(2 * m) * (9.210340371976184f / 256.0f)); // ln(1e4)/256
    float ang = (float)l * div;
    float pe = (d & 1) ? cosf(ang) : sinf(ang);
    h[row * D_MODEL + d] = acc + pe;
}

// ---------------------------------------------------------------------------
// Shared fp32 tiled GEMM body: C[64x64 tile] = A[M,K(lda)] @ W[K,N] (+ bias)
// MODE 0: plain   MODE 1: relu   MODE 2: scatter to q/k/v layout [B,H,L,32]
// ---------------------------------------------------------------------------
template <int MODE>
__device__ __forceinline__ void gemm_body(const float* __restrict__ A, int lda,
                                          const float* __restrict__ W, int N,
                                          const float* __restrict__ bias, bool doBias,
                                          float* __restrict__ C, int K,
                                          int m0, int n0) {
    __shared__ float As[16][68];
    __shared__ float Ws[16][68];
    const int t  = threadIdx.x;
    const int tx = t & 15, ty = t >> 4;
    float acc[4][4] = {};
    for (int k0 = 0; k0 < K; k0 += 16) {
        {
            int mr = t >> 2, kc = (t & 3) * 4;
            float4 av = *(const float4*)&A[(size_t)(m0 + mr) * lda + k0 + kc];
            As[kc + 0][mr] = av.x; As[kc + 1][mr] = av.y;
            As[kc + 2][mr] = av.z; As[kc + 3][mr] = av.w;
            int kr = t >> 4, nc = (t & 15) * 4;
            *(float4*)&Ws[kr][nc] = *(const float4*)&W[(size_t)(k0 + kr) * N + n0 + nc];
        }
        __syncthreads();
#pragma unroll
        for (int k = 0; k < 16; ++k) {
            float4 a4 = *(const float4*)&As[k][ty * 4];
            float4 w4 = *(const float4*)&Ws[k][tx * 4];
            float av[4] = {a4.x, a4.y, a4.z, a4.w};
            float wv[4] = {w4.x, w4.y, w4.z, w4.w};
#pragma unroll
            for (int i = 0; i < 4; ++i)
#pragma unroll
                for (int j = 0; j < 4; ++j) acc[i][j] += av[i] * wv[j];
        }
        __syncthreads();
    }
#pragma unroll
    for (int i = 0; i < 4; ++i) {
        int row = m0 + ty * 4 + i;
#pragma unroll
        for (int j = 0; j < 4; ++j) {
            int col = n0 + tx * 4 + j;
            float v = acc[i][j];
            if (doBias) v += bias[col];
            if (MODE == 1) v = fmaxf(v, 0.f);
            if (MODE == 2) {
                int bb = row >> 11, ll = row & (LSEQ - 1);
                int hh = col >> 5, dd = col & 31;
                C[(((size_t)(bb * NHEAD + hh) * LSEQ) + ll) * D_K + dd] = v;
            } else {
                C[(size_t)row * N + col] = v;
            }
        }
    }
}

// QKV fused: blockIdx.z selects {wq,wk,wv}; scatters to [B,H,L,32] at out+z*1M.
__global__ __launch_bounds__(256) void k_qkv(const float* __restrict__ A,
                                             const float* __restrict__ wq,
                                             const float* __restrict__ wk,
                                             const float* __restrict__ wv,
                                             const float* __restrict__ bq,
                                             const float* __restrict__ bk,
                                             const float* __restrict__ bv,
                                             float* __restrict__ out) {
    int z = blockIdx.z;
    const float* W = z == 0 ? wq : (z == 1 ? wk : wv);
    const float* B = z == 0 ? bq : (z == 1 ? bk : bv);
    gemm_body<2>(A, 256, W, 256, B, true, out + (size_t)z * (1 << 20), 256,
                 blockIdx.x * 64, blockIdx.y * 64);
}

// split-K GEMM: blockIdx.z = K-half; partial z to Cbase + z*1M; bias on z=0 only.
__global__ __launch_bounds__(256) void k_gemm_sk(const float* __restrict__ A, int lda,
                                                 const float* __restrict__ W,
                                                 const float* __restrict__ bias,
                                                 float* __restrict__ Cbase,
                                                 int N, int Ksub) {
    int z = blockIdx.z;
    gemm_body<0>(A + (size_t)z * Ksub, lda, W + (size_t)z * Ksub * N, N, bias, z == 0,
                 Cbase + (size_t)z * (1 << 20), Ksub, blockIdx.x * 64, blockIdx.y * 64);
}

// ff1: relu GEMM, N=1024
__global__ __launch_bounds__(256) void k_ff1(const float* __restrict__ A,
                                             const float* __restrict__ W,
                                             const float* __restrict__ bias,
                                             float* __restrict__ C) {
    gemm_body<1>(A, 256, W, 1024, bias, true, C, 256, blockIdx.x * 64, blockIdx.y * 64);
}

// ---------------------------------------------------------------------------
// Fused ProbSparse attention — R18 winner + packed-float2 QK (v_pk_fma_f32
// target) + ONE barrier per phase (stage moved after compute; slot (t+4)%5
// cannot collide with any slot read in phases t/t+1 when waves are kept
// within one phase by the single barrier).
// ---------------------------------------------------------------------------
__device__ __forceinline__ unsigned int sortkey(float f) {
    unsigned int u = __float_as_uint(f);
    return (u & 0x80000000u) ? ~u : (u | 0x80000000u);
}
__device__ __forceinline__ float key2f(unsigned int u) {
    unsigned int b = (u & 0x80000000u) ? (u ^ 0x80000000u) : ~u;
    return __uint_as_float(b);
}
__device__ __forceinline__ void gload_lds16(const float* src, float* ldsDst) {
    __builtin_amdgcn_global_load_lds(
        (const __attribute__((address_space(1))) unsigned int*)src,
        (__attribute__((address_space(3))) unsigned int*)ldsDst,
        16, 0, 0);
}

__global__ __launch_bounds__(256, 3) void k_attn(const float* __restrict__ Q,
                                                 const float* __restrict__ Kt,
                                                 const float* __restrict__ Vt,
                                                 float* __restrict__ ctxb) {
    __shared__ float          Kl[5][2048];      // 40 KB  K tile 5-slot pipeline
    __shared__ unsigned int   lvk[4][2][CAP];   // 4 KB   candidate keys
    __shared__ unsigned short lix[4][2][CAP];   // 2 KB   candidate indices
    __shared__ int            lcnt[4][2];

    const int tid   = threadIdx.x;
    const int lane  = tid & 63;
    const int wid   = tid >> 6;
    // XCD swizzle: grid 4096 = 8 XCDs x 512 (bijective).
    const int lbid  = (blockIdx.x & 7) * 512 + (blockIdx.x >> 3);
    const int bh    = lbid >> 8;                // 16 bh x 256 chunks
    const int chunk = lbid & 255;
    const int row0  = chunk * 8 + wid * 2;      // 2 rows per wave
    const int b     = bh >> 3, hh = bh & 7;
    const int h     = lane >> 5;                // d-half owned by this lane
    const int p     = lane & 31;

    const float* Kb = Kt + (size_t)bh * LSEQ * D_K;
    const float* Vb = Vt + (size_t)bh * LSEQ * D_K;
    const float* qp = Q + ((size_t)bh * LSEQ + row0) * D_K;

    const float scale = 0.17677669529663687f;   // 1/sqrt(32)
    float q0[16], q1[16];
#pragma unroll
    for (int i = 0; i < 16; ++i) {
        q0[i] = qp[h * 16 + i] * scale;
        q1[i] = qp[32 + h * 16 + i] * scale;
    }

    // Stage tile T: wave wid stages granules g = wid*2+{0,1} (g in 0..7).
    // Granule g holds dim-chunk (g&3) of keys 2p + (g>>2), half h, for all p.
#define STAGE(T, SLOT)                                                          \
    {                                                                           \
        const int g0_ = wid * 2, g1_ = wid * 2 + 1;                             \
        gload_lds16(Kb + (size_t)(T) * 2048 + (2 * p + (g0_ >> 2)) * 32         \
                        + h * 16 + (g0_ & 3) * 4, &Kl[SLOT][g0_ * 256]);        \
        gload_lds16(Kb + (size_t)(T) * 2048 + (2 * p + (g1_ >> 2)) * 32         \
                        + h * 16 + (g1_ & 3) * 4, &Kl[SLOT][g1_ * 256]);        \
    }

    // ---- single pass: packed half-dots -> combine -> registers ---------
    unsigned int k0[32], k1[32];
    unsigned int lm0 = 0u, lm1 = 0u;

    STAGE(0, 0)
    STAGE(1, 1)
    STAGE(2, 2)
    STAGE(3, 3)

#pragma unroll
    for (int t = 0; t < 32; ++t) {
        const int slot = t % 5;               // literal under full unroll
        // tile t's 2 loads complete when outstanding <= 2*(tiles issued after t)
        if      (t <= 28) asm volatile("s_waitcnt vmcnt(6)" ::: "memory");
        else if (t == 29) asm volatile("s_waitcnt vmcnt(4)" ::: "memory");
        else if (t == 30) asm volatile("s_waitcnt vmcnt(2)" ::: "memory");
        else              asm volatile("s_waitcnt vmcnt(0)" ::: "memory");
        __builtin_amdgcn_s_barrier();

        // a = {row0 dot key2p, row0 dot key2p+1}, e = same for row1 (packed)
        v2f a = {0.f, 0.f}, e = {0.f, 0.f};
#pragma unroll
        for (int c = 0; c < 4; ++c) {
            float4 kva = *(const float4*)&Kl[slot][c * 256 + lane * 4];        // key 2p
            float4 kvb = *(const float4*)&Kl[slot][(4 + c) * 256 + lane * 4];  // key 2p+1
            v2f kx = {kva.x, kvb.x}, ky = {kva.y, kvb.y};
            v2f kz = {kva.z, kvb.z}, kw = {kva.w, kvb.w};
            a += q0[c*4+0] * kx; a += q0[c*4+1] * ky;
            a += q0[c*4+2] * kz; a += q0[c*4+3] * kw;
            e += q1[c*4+0] * kx; e += q1[c*4+1] * ky;
            e += q1[c*4+2] * kz; e += q1[c*4+3] * kw;
        }
        float fA0 = a.x + __shfl_xor(a.x, 32);
        float fB0 = a.y + __shfl_xor(a.y, 32);
        float fA1 = e.x + __shfl_xor(e.x, 32);
        float fB1 = e.y + __shfl_xor(e.y, 32);
        k0[t] = sortkey(h ? fB0 : fA0);       // lane keeps key 2p+h
        k1[t] = sortkey(h ? fB1 : fA1);
        if (k0[t] > lm0) lm0 = k0[t];
        if (k1[t] > lm1) lm1 = k1[t];

        if (t + 4 < 32) STAGE(t + 4, (t + 4) % 5)
    }

    // ---- pivot per row: bitonic-sort 64 lane-maxes, broadcast via shfl --
    unsigned int Tpiv[2];
    float        rmaxf[2];
#pragma unroll
    for (int r = 0; r < 2; ++r) {
        unsigned int v = r ? lm1 : lm0;
#pragma unroll
        for (int k = 2; k <= 64; k <<= 1) {
#pragma unroll
            for (int j = k >> 1; j >= 1; j >>= 1) {
                unsigned int pv = (unsigned int)__shfl_xor((int)v, j);
                bool lower = ((lane & j) == 0);
                bool up    = ((lane & k) == 0);
                unsigned int mn = v < pv ? v : pv;
                unsigned int mx = v < pv ? pv : v;
                v = (lower == up) ? mn : mx;
            }
        }
        Tpiv[r]  = (unsigned int)__shfl((int)v, 26);  // 38th-largest lane-max
        rmaxf[r] = key2f((unsigned int)__shfl((int)v, 63));
    }
    if (lane < 2) lcnt[wid][lane] = 0;

    // ---- push candidates >= pivot from registers -----------------------
#pragma unroll
    for (int j = 0; j < 32; ++j) {
        if (k0[j] >= Tpiv[0]) {
            int s = atomicAdd(&lcnt[wid][0], 1);
            if (s < CAP) { lvk[wid][0][s] = k0[j]; lix[wid][0][s] = (unsigned short)(j * 64 + 2 * p + h); }
        }
        if (k1[j] >= Tpiv[1]) {
            int s = atomicAdd(&lcnt[wid][1], 1);
            if (s < CAP) { lvk[wid][1][s] = k1[j]; lix[wid][1][s] = (unsigned short)(j * 64 + 2 * p + h); }
        }
    }

    // ---- per-row: exact threshold (bitonic), softmax, batched PV -------
#pragma unroll
    for (int r = 0; r < 2; ++r) {
        int cnt = lcnt[wid][r]; if (cnt > CAP) cnt = CAP;

        unsigned int thrkey;
        if (cnt <= 64) {
            // 64-wide bitonic on v0 only (common case, E[cnt]~56)
            unsigned int v0 = (lane < cnt) ? lvk[wid][r][lane] : 0u;
#pragma unroll
            for (int k = 2; k <= 64; k <<= 1) {
#pragma unroll
                for (int j = k >> 1; j >= 1; j >>= 1) {
                    unsigned int pv = (unsigned int)__shfl_xor((int)v0, j);
                    bool lower = ((lane & j) == 0);
                    bool up    = ((lane & k) == 0);
                    unsigned int mn = v0 < pv ? v0 : pv;
                    unsigned int mx = v0 < pv ? pv : v0;
                    v0 = (lower == up) ? mn : mx;
                }
            }
            thrkey = (unsigned int)__shfl((int)v0, 26);   // ascending idx 64-38
        } else {
            unsigned int v0 = (lane < cnt)      ? lvk[wid][r][lane]      : 0u;
            unsigned int v1 = (64 + lane < cnt) ? lvk[wid][r][64 + lane] : 0u;
#pragma unroll
            for (int k = 2; k <= 128; k <<= 1) {
#pragma unroll
                for (int j = k >> 1; j >= 1; j >>= 1) {
                    if (j >= 64) {
                        bool up0 = ((lane & k) == 0);
                        unsigned int mn = v0 < v1 ? v0 : v1;
                        unsigned int mx = v0 < v1 ? v1 : v0;
                        v0 = up0 ? mn : mx;
                        v1 = up0 ? mx : mn;
                    } else {
                        unsigned int pp0 = (unsigned int)__shfl_xor((int)v0, j);
                        unsigned int pp1 = (unsigned int)__shfl_xor((int)v1, j);
                        bool lower = ((lane & j) == 0);
                        bool up0 = (((lane) & k) == 0);
                        bool up1 = (((64 + lane) & k) == 0);
                        v0 = (lower == up0) ? (v0 < pp0 ? v0 : pp0) : (v0 < pp0 ? pp0 : v0);
                        v1 = (lower == up1) ? (v1 < pp1 ? v1 : pp1) : (v1 < pp1 ? pp1 : v1);
                    }
                }
            }
            thrkey = (unsigned int)__shfl((int)v1, 26);   // ascending idx 90
        }

        float psum = 0.f;
        for (int i = lane; i < cnt; i += 64) {
            unsigned int key = lvk[wid][r][i];
            if (key >= thrkey) psum += __expf(key2f(key) - rmaxf[r]);
        }
#pragma unroll
        for (int off = 32; off >= 1; off >>= 1) psum += __shfl_xor(psum, off);
        float inv = 1.0f / psum;

        // PV: 8-wide batches of independent gathers (breaks serial chain)
        float acc = 0.f;
        for (int i0 = h; i0 < cnt; i0 += 16) {
            float wgt0, wgt1, wgt2, wgt3, wgt4, wgt5, wgt6, wgt7;
            int   ix0, ix1, ix2, ix3, ix4, ix5, ix6, ix7;
#define PREP(U, W, X)                                                           \
            {                                                                   \
                int i = i0 + 2 * (U);                                           \
                bool ok = i < cnt;                                              \
                unsigned int key = ok ? lvk[wid][r][i] : 0u;                    \
                W = (ok && key >= thrkey) ? __expf(key2f(key) - rmaxf[r]) : 0.f;\
                X = ok ? (int)lix[wid][r][i] : 0;                               \
            }
            PREP(0, wgt0, ix0) PREP(1, wgt1, ix1) PREP(2, wgt2, ix2) PREP(3, wgt3, ix3)
            PREP(4, wgt4, ix4) PREP(5, wgt5, ix5) PREP(6, wgt6, ix6) PREP(7, wgt7, ix7)
#undef PREP
            acc += wgt0 * Vb[(size_t)ix0 * D_K + p];
            acc += wgt1 * Vb[(size_t)ix1 * D_K + p];
            acc += wgt2 * Vb[(size_t)ix2 * D_K + p];
            acc += wgt3 * Vb[(size_t)ix3 * D_K + p];
            acc += wgt4 * Vb[(size_t)ix4 * D_K + p];
            acc += wgt5 * Vb[(size_t)ix5 * D_K + p];
            acc += wgt6 * Vb[(size_t)ix6 * D_K + p];
            acc += wgt7 * Vb[(size_t)ix7 * D_K + p];
        }
        acc += __shfl_xor(acc, 32);
        if (lane < 32)
            ctxb[((size_t)(b * LSEQ) + row0 + r) * D_MODEL + hh * D_K + p] = acc * inv;
    }
}

// ---------------------------------------------------------------------------
// Residual add (two partials) + LayerNorm over 256, in place into h.
// ---------------------------------------------------------------------------
__global__ __launch_bounds__(64) void k_addln2(float* __restrict__ h,
                                               const float* __restrict__ a1,
                                               const float* __restrict__ a2,
                                               const float* __restrict__ g,
                                               const float* __restrict__ bb) {
    int row = blockIdx.x, lane = threadIdx.x;
    float4 hv = *(const float4*)&h[(size_t)row * D_MODEL + lane * 4];
    float4 v1 = *(const float4*)&a1[(size_t)row * D_MODEL + lane * 4];
    float4 v2 = *(const float4*)&a2[(size_t)row * D_MODEL + lane * 4];
    float x0 = hv.x + v1.x + v2.x, x1 = hv.y + v1.y + v2.y;
    float x2 = hv.z + v1.z + v2.z, x3 = hv.w + v1.w + v2.w;
    float s = x0 + x1 + x2 + x3;
#pragma unroll
    for (int off = 32; off >= 1; off >>= 1) s += __shfl_xor(s, off);
    float mean = s * (1.0f / 256.0f);
    float d0 = x0 - mean, d1 = x1 - mean, d2 = x2 - mean, d3 = x3 - mean;
    float vs = d0 * d0 + d1 * d1 + d2 * d2 + d3 * d3;
#pragma unroll
    for (int off = 32; off >= 1; off >>= 1) vs += __shfl_xor(vs, off);
    float inv = rsqrtf(vs * (1.0f / 256.0f) + 1e-5f);
    float4 gv = *(const float4*)&g[lane * 4];
    float4 bv = *(const float4*)&bb[lane * 4];
    float4 o;
    o.x = d0 * inv * gv.x + bv.x;
    o.y = d1 * inv * gv.y + bv.y;
    o.z = d2 * inv * gv.z + bv.z;
    o.w = d3 * inv * gv.w + bv.w;
    *(float4*)&h[(size_t)row * D_MODEL + lane * 4] = o;
}

// ---------------------------------------------------------------------------
// Decoder head
// ---------------------------------------------------------------------------
__global__ __launch_bounds__(64) void k_dec(const float* __restrict__ h,
                                            const float* __restrict__ w,
                                            const float* __restrict__ b,
                                            float* __restrict__ out) {
    int row = blockIdx.x, lane = threadIdx.x;
    int c = lane & 7, part = lane >> 3;   // 8 parts x 32 dims
    float acc = 0.f;
    int d0 = part * 32;
#pragma unroll
    for (int dd = 0; dd < 32; ++dd) acc += h[(size_t)row * D_MODEL + d0 + dd] * w[(d0 + dd) * 8 + c];
    acc += __shfl_xor(acc, 8);
    acc += __shfl_xor(acc, 16);
    acc += __shfl_xor(acc, 32);
    if (lane < 8) out[(size_t)row * 8 + c] = acc + b[c];
}

// ---------------------------------------------------------------------------
extern "C" void kernel_launch(void* const* d_in, const int* in_sizes, int n_in,
                              void* d_out, int out_size, void* d_ws, size_t ws_size,
                              hipStream_t stream) {
    const float* x     = (const float*)d_in[0];
    const float* emb_w = (const float*)d_in[1];
    const float* emb_b = (const float*)d_in[2];
    const float* wq    = (const float*)d_in[3];
    const float* bq    = (const float*)d_in[4];
    const float* wk    = (const float*)d_in[5];
    const float* bk    = (const float*)d_in[6];
    const float* wv    = (const float*)d_in[7];
    const float* bv    = (const float*)d_in[8];
    const float* wo    = (const float*)d_in[9];
    const float* bo    = (const float*)d_in[10];
    const float* ln1_g = (const float*)d_in[11];
    const float* ln1_b = (const float*)d_in[12];
    const float* ln2_g = (const float*)d_in[13];
    const float* ln2_b = (const float*)d_in[14];
    const float* ff1_w = (const float*)d_in[15];
    const float* ff1_b = (const float*)d_in[16];
    const float* ff2_w = (const float*)d_in[17];
    const float* ff2_b = (const float*)d_in[18];
    const float* dec_w = (const float*)d_in[19];
    const float* dec_b = (const float*)d_in[20];

    float* ws   = (float*)d_ws;
    float* h    = ws;                      // 4096*256   = 1M floats
    float* qb   = h    + (1 << 20);        // qb/kb/vb: [B,H,L,32] each 1M
    float* kb   = qb   + (1 << 20);
    float* vb   = kb   + (1 << 20);
    float* ctxb = vb   + (1 << 20);
    float* ffb  = ctxb + (1 << 20);        // 4096*1024 = 4M

    k_embed<<<ROWS, 256, 0, stream>>>(x, emb_w, emb_b, h);

    for (int l = 0; l < 2; ++l) {
        const float* wql = wq + (size_t)l * 65536;  const float* bql = bq + l * 256;
        const float* wkl = wk + (size_t)l * 65536;  const float* bkl = bk + l * 256;
        const float* wvl = wv + (size_t)l * 65536;  const float* bvl = bv + l * 256;
        const float* wol = wo + (size_t)l * 65536;  const float* bol = bo + l * 256;

        dim3 gq(64, 4, 3);
        k_qkv<<<gq, 256, 0, stream>>>(h, wql, wkl, wvl, bql, bkl, bvl, qb);

        k_attn<<<NHEAD * BATCH * 256, 256, 0, stream>>>(qb, kb, vb, ctxb);

        // wo: split-K (128 x 2) -> partials in qb, kb (free after attn)
        dim3 gsk(64, 4, 2);
        k_gemm_sk<<<gsk, 256, 0, stream>>>(ctxb, 256, wol, bol, qb, 256, 128);
        k_addln2<<<ROWS, 64, 0, stream>>>(h, qb, kb, ln1_g + l * 256, ln1_b + l * 256);

        dim3 gf1(64, 16);
        k_ff1<<<gf1, 256, 0, stream>>>(h, ff1_w + (size_t)l * 262144, ff1_b + l * 1024, ffb);

        // ff2: split-K (512 x 2) -> partials in qb, kb
        k_gemm_sk<<<gsk, 256, 0, stream>>>(ffb, 1024, ff2_w + (size_t)l * 262144,
                                           ff2_b + l * 256, qb, 256, 512);
        k_addln2<<<ROWS, 64, 0, stream>>>(h, qb, kb, ln2_g + l * 256, ln2_b + l * 256);
    }

    k_dec<<<ROWS, 64, 0, stream>>>(h, dec_w, dec_b, (float*)d_out);
}